// Round 3
// baseline (262.393 us; speedup 1.0000x reference)
//
#include <hip/hip_runtime.h>

// Skewed MAE: mean(|p - t| * exp(sign(t - p) * (2t - 1)))
//
// R5: hybrid cache-path probe. Session model: write path ~6.9 TB/s (fills),
// pure-HBM read path ~3.35 TB/s (R3/R4 nt), and R0 showed both-allocating
// loads couple L3+HBM to 1.34+1.34. Untested point: yp stays nt (pure HBM
// stream, zero L3 interaction), yt uses regular allocating loads (134 MB
// fits the 256 MB L3 and nothing else allocates -> stays resident across
// iterations, served by MALL in parallel with the HBM stream).
// ONE variable vs R4: yt load cache policy.
// Predict: win -> stage1 FETCH ~134 MB, stage1 45-60us, total 220-235.
//          null (+-4us) -> read ceiling confirmed, declare roofline.
//          +10-20us -> allocate coupling returns, revert to R4.

#define BLOCK 256
#define GRID 2048
#define UNROLL 4

typedef float f32x4 __attribute__((ext_vector_type(4)));

__device__ __forceinline__ float skew_elem(float p, float t) {
    float d = p - t;
    float lam = __builtin_fmaf(2.0f, t, -1.0f);     // 2t - 1
    float s = (d < 0.0f) ? lam : -lam;              // sign(t-p)*lam; d==0 -> |d|=0
    return fabsf(d) * __expf(s);
}

__device__ __forceinline__ float block_reduce(float acc) {
    #pragma unroll
    for (int off = 32; off > 0; off >>= 1)
        acc += __shfl_down(acc, off, 64);
    __shared__ float smem[BLOCK / 64];
    int lane = threadIdx.x & 63;
    int wave = threadIdx.x >> 6;
    if (lane == 0) smem[wave] = acc;
    __syncthreads();
    float s = 0.0f;
    #pragma unroll
    for (int w = 0; w < BLOCK / 64; ++w) s += smem[w];
    return s;   // valid in all threads (cheap; avoids a second sync)
}

__global__ __launch_bounds__(BLOCK, 8) void skewed_mae_stage1(
        const f32x4* __restrict__ yp4, const f32x4* __restrict__ yt4,
        const float* __restrict__ yp, const float* __restrict__ yt,
        float* __restrict__ partials, int n4, int n, float inv_n) {
    const int tid = blockIdx.x * BLOCK + threadIdx.x;
    const int stride = GRID * BLOCK;

    float acc = 0.0f;

    int base = tid;
    for (; base + (UNROLL - 1) * stride < n4; base += UNROLL * stride) {
        f32x4 p[UNROLL], t[UNROLL];
        // yp: non-temporal (pure HBM stream, no L3 allocate).
        // yt: regular allocating load (L3-resident across iterations).
        #pragma unroll
        for (int k = 0; k < UNROLL; ++k) {
            p[k] = __builtin_nontemporal_load(yp4 + base + k * stride);
            t[k] = yt4[base + k * stride];
        }
        __builtin_amdgcn_sched_barrier(0);
        #pragma unroll
        for (int k = 0; k < UNROLL; ++k) {
            acc += skew_elem(p[k].x, t[k].x);
            acc += skew_elem(p[k].y, t[k].y);
            acc += skew_elem(p[k].z, t[k].z);
            acc += skew_elem(p[k].w, t[k].w);
        }
    }
    for (; base < n4; base += stride) {
        f32x4 p = __builtin_nontemporal_load(yp4 + base);
        f32x4 t = yt4[base];
        acc += skew_elem(p.x, t.x);
        acc += skew_elem(p.y, t.y);
        acc += skew_elem(p.z, t.z);
        acc += skew_elem(p.w, t.w);
    }
    for (int i = n4 * 4 + tid; i < n; i += stride) {
        acc += skew_elem(yp[i], yt[i]);
    }
    acc *= inv_n;

    float s = block_reduce(acc);
    if (threadIdx.x == 0) partials[blockIdx.x] = s;
}

// Stage 2: one block reduces GRID partials and writes the scalar output.
__global__ __launch_bounds__(BLOCK) void skewed_mae_stage2(
        const float* __restrict__ partials, float* __restrict__ out) {
    float acc = 0.0f;
    #pragma unroll
    for (int k = 0; k < GRID / BLOCK; ++k)
        acc += partials[k * BLOCK + threadIdx.x];
    float s = block_reduce(acc);
    if (threadIdx.x == 0) out[0] = s;
}

extern "C" void kernel_launch(void* const* d_in, const int* in_sizes, int n_in,
                              void* d_out, int out_size, void* d_ws, size_t ws_size,
                              hipStream_t stream) {
    const float* yp = (const float*)d_in[0];
    const float* yt = (const float*)d_in[1];
    float* out = (float*)d_out;
    float* partials = (float*)d_ws;    // GRID floats = 8 KB scratch
    int n = in_sizes[0];
    int n4 = n / 4;

    skewed_mae_stage1<<<GRID, BLOCK, 0, stream>>>(
        (const f32x4*)yp, (const f32x4*)yt, yp, yt, partials, n4, n,
        1.0f / (float)n);
    skewed_mae_stage2<<<1, BLOCK, 0, stream>>>(partials, out);
}

// Round 4
// 256.405 us; speedup vs baseline: 1.0234x; 1.0234x over previous
//
#include <hip/hip_runtime.h>

// Skewed MAE: mean(|p - t| * exp(sign(t - p) * (2t - 1)))
//
// R6 = revert to R4 (best measured: 252.9us), per R5's pre-committed
// regression branch (+9.5us from yt allocating loads coupling with the
// harness restore fills).
//
// SESSION ROOFLINE MODEL (R0-R5 evidence):
//   - writes (posted): ~6.9 TB/s   [rocclr fills, 512MiB/78us]
//   - reads: ~3.35-3.4 TB/s CU-bound return path, INDEPENDENT of source:
//       R5 ord103: ~100% L3-hit dispatch (FETCH 67KB) = 79.2us
//       R3/R4 pure-HBM nt stream                      = ~78-80us
//       m13 copy 6.29 TB/s = 3.15 read + 3.15 write   (consistent)
//   - allocate-coupling (any allocating input stream while fills run)
//     costs ~10-25us (R0: 2.68 TB/s; R5: +9.5us total).
// Floor: 268.4 MB / 3.4 TB/s = 79us stage1 (measured 78-80, within 2%);
// + ~6us stage2/launch; + ~156us harness restore fills (not ours).
// Both streams nt is the optimal policy. Expect total ~253 +/- 3us.

#define BLOCK 256
#define GRID 2048
#define UNROLL 4

typedef float f32x4 __attribute__((ext_vector_type(4)));

__device__ __forceinline__ float skew_elem(float p, float t) {
    float d = p - t;
    float lam = __builtin_fmaf(2.0f, t, -1.0f);     // 2t - 1
    float s = (d < 0.0f) ? lam : -lam;              // sign(t-p)*lam; d==0 -> |d|=0
    return fabsf(d) * __expf(s);
}

__device__ __forceinline__ float block_reduce(float acc) {
    #pragma unroll
    for (int off = 32; off > 0; off >>= 1)
        acc += __shfl_down(acc, off, 64);
    __shared__ float smem[BLOCK / 64];
    int lane = threadIdx.x & 63;
    int wave = threadIdx.x >> 6;
    if (lane == 0) smem[wave] = acc;
    __syncthreads();
    float s = 0.0f;
    #pragma unroll
    for (int w = 0; w < BLOCK / 64; ++w) s += smem[w];
    return s;   // valid in all threads (cheap; avoids a second sync)
}

__global__ __launch_bounds__(BLOCK, 8) void skewed_mae_stage1(
        const f32x4* __restrict__ yp4, const f32x4* __restrict__ yt4,
        const float* __restrict__ yp, const float* __restrict__ yt,
        float* __restrict__ partials, int n4, int n, float inv_n) {
    const int tid = blockIdx.x * BLOCK + threadIdx.x;
    const int stride = GRID * BLOCK;

    float acc = 0.0f;

    int base = tid;
    for (; base + (UNROLL - 1) * stride < n4; base += UNROLL * stride) {
        f32x4 p[UNROLL], t[UNROLL];
        #pragma unroll
        for (int k = 0; k < UNROLL; ++k) {
            p[k] = __builtin_nontemporal_load(yp4 + base + k * stride);
            t[k] = __builtin_nontemporal_load(yt4 + base + k * stride);
        }
        __builtin_amdgcn_sched_barrier(0);
        #pragma unroll
        for (int k = 0; k < UNROLL; ++k) {
            acc += skew_elem(p[k].x, t[k].x);
            acc += skew_elem(p[k].y, t[k].y);
            acc += skew_elem(p[k].z, t[k].z);
            acc += skew_elem(p[k].w, t[k].w);
        }
    }
    for (; base < n4; base += stride) {
        f32x4 p = __builtin_nontemporal_load(yp4 + base);
        f32x4 t = __builtin_nontemporal_load(yt4 + base);
        acc += skew_elem(p.x, t.x);
        acc += skew_elem(p.y, t.y);
        acc += skew_elem(p.z, t.z);
        acc += skew_elem(p.w, t.w);
    }
    for (int i = n4 * 4 + tid; i < n; i += stride) {
        acc += skew_elem(yp[i], yt[i]);
    }
    acc *= inv_n;

    float s = block_reduce(acc);
    if (threadIdx.x == 0) partials[blockIdx.x] = s;
}

// Stage 2: one block reduces GRID partials and writes the scalar output.
__global__ __launch_bounds__(BLOCK) void skewed_mae_stage2(
        const float* __restrict__ partials, float* __restrict__ out) {
    float acc = 0.0f;
    #pragma unroll
    for (int k = 0; k < GRID / BLOCK; ++k)
        acc += partials[k * BLOCK + threadIdx.x];
    float s = block_reduce(acc);
    if (threadIdx.x == 0) out[0] = s;
}

extern "C" void kernel_launch(void* const* d_in, const int* in_sizes, int n_in,
                              void* d_out, int out_size, void* d_ws, size_t ws_size,
                              hipStream_t stream) {
    const float* yp = (const float*)d_in[0];
    const float* yt = (const float*)d_in[1];
    float* out = (float*)d_out;
    float* partials = (float*)d_ws;    // GRID floats = 8 KB scratch
    int n = in_sizes[0];
    int n4 = n / 4;

    skewed_mae_stage1<<<GRID, BLOCK, 0, stream>>>(
        (const f32x4*)yp, (const f32x4*)yt, yp, yt, partials, n4, n,
        1.0f / (float)n);
    skewed_mae_stage2<<<1, BLOCK, 0, stream>>>(partials, out);
}